// Round 3
// baseline (904.927 us; speedup 1.0000x reference)
//
#include <hip/hip_runtime.h>

// NonMaxSuppression fused single-pass: 3x3 local max + thr>=0.6 + 10px border,
// ordered (y,x) coords via decoupled-lookback stream compaction.
// Input fixed: (16,1,1536,1536) fp32.
#define W 1536
#define H 1536
#define NB 16
#define ROWS_PER_TILE 16
#define CHUNKS_PER_ROW 24                       // 1536 / 64
#define BLOCK (ROWS_PER_TILE * CHUNKS_PER_ROW)  // 384 threads = 6 waves
#define NBLK (NB * H / ROWS_PER_TILE)           // 1536 blocks
#define REP_THR 0.6f

__device__ __forceinline__ float max3f(float a, float b, float c) {
    return fmaxf(fmaxf(a, b), c);  // -> v_max3_f32
}

__global__ __launch_bounds__(BLOCK) void nms_fused(const float* __restrict__ in,
                                                   unsigned long long* __restrict__ desc,
                                                   int* __restrict__ out, unsigned int K) {
    const unsigned t = threadIdx.x;
    const unsigned lane = t & 63u;
    const unsigned wv = t >> 6;                  // 0..5
    const unsigned blk = blockIdx.x;
    const unsigned b = blk / 96u;                // image
    const unsigned ytile = blk - b * 96u;
    const unsigned r = t / CHUNKS_PER_ROW;       // row within tile
    const unsigned c = t - r * CHUNKS_PER_ROW;   // 64-px chunk within row
    const unsigned yy = ytile * ROWS_PER_TILE + r;

    // ---- predicate: 64 consecutive px (flat order), separable rolling 3x3 max ----
    unsigned long long bits = 0ull;
    if (yy >= 10u && yy < (unsigned)(H - 10)) {
        const float* base = in + ((size_t)(b * H + yy) - 1) * W + c * 64u;  // row y-1
        float4 a0 = *(const float4*)(base);
        float4 a1 = *(const float4*)(base + W);
        float4 a2 = *(const float4*)(base + 2 * W);
        float4 p0 = *(const float4*)(base - 4);
        float4 p1 = *(const float4*)(base + W - 4);
        float4 p2 = *(const float4*)(base + 2 * W - 4);
        float pw = max3f(p0.w, p1.w, p2.w);      // vmax of col -1
        float4 vc;                               // vmax of cols 0..3 (includes center row)
        vc.x = max3f(a0.x, a1.x, a2.x);
        vc.y = max3f(a0.y, a1.y, a2.y);
        vc.z = max3f(a0.z, a1.z, a2.z);
        vc.w = max3f(a0.w, a1.w, a2.w);
        float4 ctr = a1;                         // center-row values, cols 0..3
#pragma unroll 4
        for (int k = 0; k < 16; ++k) {
            float4 n0 = *(const float4*)(base + (4 * k + 4));
            float4 n1 = *(const float4*)(base + W + (4 * k + 4));
            float4 n2 = *(const float4*)(base + 2 * W + (4 * k + 4));
            float4 vn;
            vn.x = max3f(n0.x, n1.x, n2.x);
            vn.y = max3f(n0.y, n1.y, n2.y);
            vn.z = max3f(n0.z, n1.z, n2.z);
            vn.w = max3f(n0.w, n1.w, n2.w);
            unsigned g = 0;
            g |= (ctr.x >= fmaxf(max3f(pw,   vc.x, vc.y), REP_THR)) ? 1u : 0u;
            g |= (ctr.y >= fmaxf(max3f(vc.x, vc.y, vc.z), REP_THR)) ? 2u : 0u;
            g |= (ctr.z >= fmaxf(max3f(vc.y, vc.z, vc.w), REP_THR)) ? 4u : 0u;
            g |= (ctr.w >= fmaxf(max3f(vc.z, vc.w, vn.x), REP_THR)) ? 8u : 0u;
            bits |= (unsigned long long)g << (4 * k);
            pw = vc.w; vc = vn; ctr = n1;
        }
        if (c == 0u) bits &= ~0x3FFull;                                  // x >= 10
        if (c == (unsigned)(CHUNKS_PER_ROW - 1)) bits &= (1ull << 54) - 1ull;  // x < 1526
    }

    // ---- block scan of survivor counts (flat thread order == flat px order) ----
    unsigned cnt = (unsigned)__popcll(bits);
    unsigned incl = cnt;
#pragma unroll
    for (int o = 1; o < 64; o <<= 1) {
        unsigned u = __shfl_up(incl, o, 64);
        if (lane >= (unsigned)o) incl += u;
    }
    __shared__ unsigned wtot[BLOCK / 64];
    __shared__ unsigned sPrefix;
    if (lane == 63u) wtot[wv] = incl;
    __syncthreads();
    unsigned wbase = 0, total = 0;
#pragma unroll
    for (int k = 0; k < BLOCK / 64; ++k) {
        unsigned wtk = wtot[k];
        wbase += ((unsigned)k < wv) ? wtk : 0u;
        total += wtk;
    }

    // ---- decoupled lookback: desc[b] = value<<2 | flag (0=inv, 1=aggregate, 2=prefix) ----
    if (t == 0u && blk != 0u)
        __hip_atomic_store(&desc[blk], ((unsigned long long)total << 2) | 1ull,
                           __ATOMIC_RELEASE, __HIP_MEMORY_SCOPE_AGENT);
    if (wv == 0u) {
        unsigned prefix = 0u;
        if (blk != 0u) {
            int wend = (int)blk;  // exclusive window end
            for (;;) {
                int idx = wend - 64 + (int)lane;
                unsigned long long d;
                for (;;) {
                    d = (idx >= 0)
                        ? __hip_atomic_load(&desc[idx], __ATOMIC_ACQUIRE, __HIP_MEMORY_SCOPE_AGENT)
                        : 2ull;  // virtual block: prefix 0, ready
                    if (__all((d & 3ull) != 0ull)) break;
                    __builtin_amdgcn_s_sleep(1);
                }
                unsigned long long pm = __ballot((d & 3ull) == 2ull);
                unsigned v = (unsigned)(d >> 2);
                unsigned contrib;
                if (pm) {
                    unsigned hp = 63u - (unsigned)__builtin_clzll(pm);  // highest prefix lane
                    contrib = (lane >= hp) ? v : 0u;  // hp: inclusive prefix; >hp: aggregates
                } else {
                    contrib = v;
                }
#pragma unroll
                for (int o = 1; o < 64; o <<= 1) contrib += __shfl_xor(contrib, o, 64);
                prefix += contrib;
                if (pm) break;
                wend -= 64;
                if (wend <= 0) break;  // unreachable safety (idx<0 lanes force pm!=0)
            }
        }
        if (lane == 0u) {
            __hip_atomic_store(&desc[blk], ((unsigned long long)(prefix + total) << 2) | 2ull,
                               __ATOMIC_RELEASE, __HIP_MEMORY_SCOPE_AGENT);
            sPrefix = prefix;
        }
    }
    __syncthreads();

    // ---- ordered scatter ----
    unsigned pos = sPrefix + wbase + (incl - cnt);
    if (bits) {
        const int x0 = (int)(c * 64u);
        const int yv = (int)yy;
        unsigned long long m = bits;
        while (m) {
            int j = __builtin_ctzll(m);
            m &= m - 1ull;
            if (pos < K) { out[pos] = yv; out[K + pos] = x0 + j; }
            ++pos;
        }
    }
}

extern "C" void kernel_launch(void* const* d_in, const int* in_sizes, int n_in,
                              void* d_out, int out_size, void* d_ws, size_t ws_size,
                              hipStream_t stream) {
    const float* in = (const float*)d_in[0];
    int* out = (int*)d_out;
    unsigned long long* desc = (unsigned long long*)d_ws;
    const unsigned K = (unsigned)(out_size / 2);
    hipMemsetAsync(d_ws, 0, NBLK * sizeof(unsigned long long), stream);  // clear 0xAA poison
    nms_fused<<<NBLK, BLOCK, 0, stream>>>(in, desc, out, K);
}

// Round 4
// 323.629 us; speedup vs baseline: 2.7962x; 2.7962x over previous
//
#include <hip/hip_runtime.h>

// NonMaxSuppression: 3x3 local max + thr>=0.6 + 10px border -> ordered (y,x) coords.
// Input fixed: (16,1,1536,1536) fp32. 3-pass compaction (no inter-block spin).
#define W 1536
#define H 1536
#define NB 16
#define ROWS_PER_TILE 16
#define CHUNKS_PER_ROW 24                       // 1536 / 64
#define BLOCK (ROWS_PER_TILE * CHUNKS_PER_ROW)  // 384 threads = 6 waves
#define NBLK (NB * H / ROWS_PER_TILE)           // 1536 blocks
#define NMASK (NBLK * BLOCK)                    // 589824 u64 masks (4.72 MB)
#define REP_THR 0.6f

__device__ __forceinline__ float max3f(float a, float b, float c) {
    return fmaxf(fmaxf(a, b), c);  // -> v_max3_f32
}

// Pass 1: thread t of block blk covers 64 px at flat offset (blk*BLOCK+t)*64.
// Separable rolling 3x3 max; 51 float4 loads / 64 px. Emits u64 mask + block count.
__global__ __launch_bounds__(BLOCK) void nms_pass1(const float* __restrict__ in,
                                                   unsigned long long* __restrict__ masks,
                                                   unsigned int* __restrict__ counts) {
    const unsigned t = threadIdx.x;
    const unsigned lane = t & 63u;
    const unsigned wv = t >> 6;
    const unsigned blk = blockIdx.x;
    const unsigned b = blk / 96u;
    const unsigned ytile = blk - b * 96u;
    const unsigned r = t / CHUNKS_PER_ROW;
    const unsigned c = t - r * CHUNKS_PER_ROW;
    const unsigned yy = ytile * ROWS_PER_TILE + r;

    unsigned long long bits = 0ull;
    if (yy >= 10u && yy < (unsigned)(H - 10)) {
        const float* base = in + ((size_t)(b * H + yy) - 1) * W + c * 64u;  // row y-1
        float4 a0 = *(const float4*)(base);
        float4 a1 = *(const float4*)(base + W);
        float4 a2 = *(const float4*)(base + 2 * W);
        float4 p0 = *(const float4*)(base - 4);
        float4 p1 = *(const float4*)(base + W - 4);
        float4 p2 = *(const float4*)(base + 2 * W - 4);
        float pw = max3f(p0.w, p1.w, p2.w);      // column max at x-1
        float4 vc;                               // column maxes, cols 0..3
        vc.x = max3f(a0.x, a1.x, a2.x);
        vc.y = max3f(a0.y, a1.y, a2.y);
        vc.z = max3f(a0.z, a1.z, a2.z);
        vc.w = max3f(a0.w, a1.w, a2.w);
        float4 ctr = a1;                         // center-row values, cols 0..3
#pragma unroll 4
        for (int k = 0; k < 16; ++k) {
            float4 n0 = *(const float4*)(base + (4 * k + 4));
            float4 n1 = *(const float4*)(base + W + (4 * k + 4));
            float4 n2 = *(const float4*)(base + 2 * W + (4 * k + 4));
            float4 vn;
            vn.x = max3f(n0.x, n1.x, n2.x);
            vn.y = max3f(n0.y, n1.y, n2.y);
            vn.z = max3f(n0.z, n1.z, n2.z);
            vn.w = max3f(n0.w, n1.w, n2.w);
            unsigned g = 0;
            g |= (ctr.x >= fmaxf(max3f(pw,   vc.x, vc.y), REP_THR)) ? 1u : 0u;
            g |= (ctr.y >= fmaxf(max3f(vc.x, vc.y, vc.z), REP_THR)) ? 2u : 0u;
            g |= (ctr.z >= fmaxf(max3f(vc.y, vc.z, vc.w), REP_THR)) ? 4u : 0u;
            g |= (ctr.w >= fmaxf(max3f(vc.z, vc.w, vn.x), REP_THR)) ? 8u : 0u;
            bits |= (unsigned long long)g << (4 * k);
            pw = vc.w; vc = vn; ctr = n1;
        }
        if (c == 0u) bits &= ~0x3FFull;                                       // x >= 10
        if (c == (unsigned)(CHUNKS_PER_ROW - 1)) bits &= (1ull << 54) - 1ull; // x < 1526
    }
    masks[(size_t)blk * BLOCK + t] = bits;

    unsigned cnt = (unsigned)__popcll(bits);
#pragma unroll
    for (int o = 32; o > 0; o >>= 1) cnt += __shfl_down(cnt, o, 64);
    __shared__ unsigned wsum[BLOCK / 64];
    if (lane == 0u) wsum[wv] = cnt;
    __syncthreads();
    if (t == 0) {
        unsigned s = 0;
#pragma unroll
        for (int k = 0; k < BLOCK / 64; ++k) s += wsum[k];
        counts[blk] = s;
    }
}

// Pass 2: single block, exclusive scan of NBLK=1536 counts (256 threads x 6 each).
__global__ __launch_bounds__(256) void nms_scan(const unsigned int* __restrict__ counts,
                                                unsigned int* __restrict__ offsets) {
    const int t = threadIdx.x;
    const int lane = t & 63, wv = t >> 6;  // 4 waves
    unsigned v[6];
    unsigned sum = 0;
#pragma unroll
    for (int k = 0; k < 6; ++k) { v[k] = counts[t * 6 + k]; sum += v[k]; }
    unsigned incl = sum;
#pragma unroll
    for (int o = 1; o < 64; o <<= 1) {
        unsigned u = __shfl_up(incl, o, 64);
        if (lane >= o) incl += u;
    }
    __shared__ unsigned wtot[4];
    if (lane == 63) wtot[wv] = incl;
    __syncthreads();
    unsigned base = incl - sum;
#pragma unroll
    for (int k = 0; k < 4; ++k) base += (k < wv) ? wtot[k] : 0u;
#pragma unroll
    for (int k = 0; k < 6; ++k) { offsets[t * 6 + k] = base; base += v[k]; }
}

// Pass 3: replay masks, block shuffle scan, ordered (y,x) scatter.
__global__ __launch_bounds__(BLOCK) void nms_pass3(const unsigned long long* __restrict__ masks,
                                                   const unsigned int* __restrict__ offsets,
                                                   int* __restrict__ out, unsigned int K) {
    const unsigned t = threadIdx.x;
    const unsigned lane = t & 63u, wv = t >> 6;
    const unsigned blk = blockIdx.x;
    unsigned long long bits = masks[(size_t)blk * BLOCK + t];
    const unsigned cnt = (unsigned)__popcll(bits);
    unsigned incl = cnt;
#pragma unroll
    for (int o = 1; o < 64; o <<= 1) {
        unsigned u = __shfl_up(incl, o, 64);
        if (lane >= (unsigned)o) incl += u;
    }
    __shared__ unsigned wtot[BLOCK / 64];
    if (lane == 63u) wtot[wv] = incl;
    __syncthreads();
    unsigned wbase = 0;
#pragma unroll
    for (int k = 0; k < BLOCK / 64; ++k) wbase += ((unsigned)k < wv) ? wtot[k] : 0u;
    unsigned pos = offsets[blk] + wbase + (incl - cnt);
    if (bits) {
        const unsigned b = blk / 96u;
        const unsigned ytile = blk - b * 96u;
        const unsigned r = t / CHUNKS_PER_ROW;
        const unsigned c = t - r * CHUNKS_PER_ROW;
        const int yv = (int)(ytile * ROWS_PER_TILE + r);
        const int x0 = (int)(c * 64u);
        while (bits) {
            int j = __builtin_ctzll(bits);
            bits &= bits - 1ull;
            if (pos < K) { out[pos] = yv; out[K + pos] = x0 + j; }
            ++pos;
        }
    }
}

extern "C" void kernel_launch(void* const* d_in, const int* in_sizes, int n_in,
                              void* d_out, int out_size, void* d_ws, size_t ws_size,
                              hipStream_t stream) {
    const float* in = (const float*)d_in[0];
    int* out = (int*)d_out;
    unsigned long long* masks = (unsigned long long*)d_ws;
    unsigned int* counts = (unsigned int*)((char*)d_ws + (size_t)NMASK * 8);
    unsigned int* offsets = counts + NBLK;
    const unsigned K = (unsigned)(out_size / 2);

    nms_pass1<<<NBLK, BLOCK, 0, stream>>>(in, masks, counts);
    nms_scan<<<1, 256, 0, stream>>>(counts, offsets);
    nms_pass3<<<NBLK, BLOCK, 0, stream>>>(masks, offsets, out, K);
}

// Round 5
// 267.191 us; speedup vs baseline: 3.3868x; 1.2112x over previous
//
#include <hip/hip_runtime.h>

// NonMaxSuppression: 3x3 local max + thr>=0.6 + 10px border -> ordered (y,x) coords.
// Input fixed: (16,1,1536,1536) fp32.
// Pass1: rolling row-strip, global_load_lds staging (each element read ONCE),
//        separable v_max3 NMS from LDS, flat u64 masks. Pass2: tiny scan.
//        Pass3: mask replay + ordered scatter.
#define W 1536
#define H 1536
#define NB 16
#define NROWS (NB * H)              // 24576
#define SH 32                       // output rows per block
#define NBLK1 (NROWS / SH)          // 768 = 3 blocks/CU exactly
#define BLOCK1 384                  // 6 waves
#define RING 8                      // LDS ring rows (48 KB)
#define CPR 24                      // u64 chunks per row (1536/64)
#define NMASK (NROWS * CPR)         // 589824 u64 = 4.72 MB
#define REP_THR 0.6f

__device__ __forceinline__ float max3f(float a, float b, float c) {
    return fmaxf(fmaxf(a, b), c);  // v_max3_f32
}

__global__ __launch_bounds__(BLOCK1) void nms_pass1(const float* __restrict__ in,
                                                    unsigned long long* __restrict__ masks,
                                                    unsigned int* __restrict__ counts) {
    __shared__ float smem[RING * W];          // 48 KB ring of raw rows
    __shared__ unsigned wsum[BLOCK1 / 64];
    const int t = threadIdx.x;
    const int lane = t & 63;
    const int wv = t >> 6;
    const int blk = blockIdx.x;
    const int img = blk / 48;                 // 48 strips per image
    const int ytile = blk - img * 48;
    const int R0 = img * H + ytile * SH;      // absolute first output row
    const int rlo = R0 - 1;                   // first staged input row (rel 0)

    // stage rows rel 4s..4s+3 into ring slots; lds dest = wave-uniform base + lane*16
    auto issue_step = [&](int s) {
        const int rel0 = 4 * s;
#pragma unroll
        for (int j = 0; j < 4; ++j) {
            int ir = rlo + rel0 + j;
            ir = ir < 0 ? 0 : (ir >= NROWS ? NROWS - 1 : ir);
            const float* g = in + (size_t)ir * W + 4 * t;
            float* l = smem + ((rel0 + j) & (RING - 1)) * W + (wv << 8);  // +wv*256 floats
            __builtin_amdgcn_global_load_lds(
                (const __attribute__((address_space(1))) unsigned int*)g,
                (__attribute__((address_space(3))) unsigned int*)l, 16, 0, 0);
        }
    };

    // per-thread window: cols 4t-1 .. 4t+4 (6 floats) of a row, read as 3 contiguous b128
    const int cl = (t == 0) ? 0 : (4 * t - 4);
    const int cr = (t == BLOCK1 - 1) ? 4 * t : (4 * t + 4);
    auto read_row = [&](int rel, float* r) {
        const float* base = smem + (rel & (RING - 1)) * W;
        float4 L = *(const float4*)(base + cl);
        float4 C = *(const float4*)(base + 4 * t);
        float4 R = *(const float4*)(base + cr);
        r[0] = L.w; r[1] = C.x; r[2] = C.y; r[3] = C.z; r[4] = C.w; r[5] = R.x;
    };

    // x-border nibble mask for cols 4t..4t+3 vs valid [10, 1526)
    unsigned colm = 0xFu;
    if (4 * t + 3 < 10) colm = 0u;            // t <= 1
    else if (4 * t < 10) colm = 0xCu;         // t == 2
    if (4 * t > 1525) colm = 0u;              // t >= 382
    else if (4 * t + 3 > 1525) colm &= 0x3u;  // t == 381

    issue_step(0);
    issue_step(1);

    float rA[6], rB[6], rC[6];
    unsigned cnt = 0;

#pragma unroll 1
    for (int s = 1; s <= SH / 4; ++s) {
        __syncthreads();                      // drain staged loads (<= step s)
        if (s == 1) { read_row(0, rA); read_row(1, rB); }
        const int yb = ytile * SH + 4 * (s - 1);   // image-local y of first output row
#pragma unroll
        for (int r = 0; r < 4; ++r) {
            read_row(4 * (s - 1) + 2 + r, rC);
            const int y = yb + r;
            unsigned nib = 0u;
            if (y >= 10 && y < H - 10) {
                float cm0 = max3f(rA[0], rB[0], rC[0]);
                float cm1 = max3f(rA[1], rB[1], rC[1]);
                float cm2 = max3f(rA[2], rB[2], rC[2]);
                float cm3 = max3f(rA[3], rB[3], rC[3]);
                float cm4 = max3f(rA[4], rB[4], rC[4]);
                float cm5 = max3f(rA[5], rB[5], rC[5]);
                nib |= (rB[1] >= fmaxf(max3f(cm0, cm1, cm2), REP_THR)) ? 1u : 0u;
                nib |= (rB[2] >= fmaxf(max3f(cm1, cm2, cm3), REP_THR)) ? 2u : 0u;
                nib |= (rB[3] >= fmaxf(max3f(cm2, cm3, cm4), REP_THR)) ? 4u : 0u;
                nib |= (rB[4] >= fmaxf(max3f(cm3, cm4, cm5), REP_THR)) ? 8u : 0u;
                nib &= colm;
            }
#pragma unroll
            for (int k = 0; k < 6; ++k) { rA[k] = rB[k]; rB[k] = rC[k]; }
            cnt += __popc(nib);
            // fold 16 lanes' nibbles -> u64 chunk (lane%16==0 holds it)
            unsigned x = nib;
            x |= __shfl_down(x, 1, 64) << 4;
            x |= __shfl_down(x, 2, 64) << 8;
            x |= __shfl_down(x, 4, 64) << 16;
            unsigned hi = __shfl_down(x, 8, 64);
            if ((lane & 15) == 0) {
                unsigned long long m64 = (unsigned long long)x | ((unsigned long long)hi << 32);
                masks[(size_t)(img * H + y) * CPR + (t >> 4)] = m64;
            }
        }
        __syncthreads();                      // all reads of step s done before overwrite
        if (s < SH / 4) issue_step(s + 1);
    }

#pragma unroll
    for (int o = 32; o > 0; o >>= 1) cnt += __shfl_down(cnt, o, 64);
    if (lane == 0) wsum[wv] = cnt;
    __syncthreads();
    if (t == 0) {
        unsigned sum = 0;
#pragma unroll
        for (int k = 0; k < BLOCK1 / 64; ++k) sum += wsum[k];
        counts[blk] = sum;
    }
}

// Pass 2: exclusive scan of 768 counts (one block, 256 threads x 3).
__global__ __launch_bounds__(256) void nms_scan(const unsigned int* __restrict__ counts,
                                                unsigned int* __restrict__ offsets) {
    const int t = threadIdx.x;
    const int lane = t & 63, wv = t >> 6;
    unsigned v0 = counts[3 * t], v1 = counts[3 * t + 1], v2 = counts[3 * t + 2];
    unsigned sum = v0 + v1 + v2;
    unsigned incl = sum;
#pragma unroll
    for (int o = 1; o < 64; o <<= 1) {
        unsigned u = __shfl_up(incl, o, 64);
        if (lane >= o) incl += u;
    }
    __shared__ unsigned wtot[4];
    if (lane == 63) wtot[wv] = incl;
    __syncthreads();
    unsigned base = incl - sum;
#pragma unroll
    for (int k = 0; k < 4; ++k) base += (k < wv) ? wtot[k] : 0u;
    offsets[3 * t] = base;
    offsets[3 * t + 1] = base + v0;
    offsets[3 * t + 2] = base + v0 + v1;
}

// Pass 3: replay masks (3 per thread), block scan, ordered (y,x) scatter.
__global__ __launch_bounds__(256) void nms_pass3(const unsigned long long* __restrict__ masks,
                                                 const unsigned int* __restrict__ offsets,
                                                 int* __restrict__ out, unsigned int K) {
    const int t = threadIdx.x, lane = t & 63, wv = t >> 6;
    const int blk = blockIdx.x;
    unsigned long long m[3];
    unsigned cnt = 0;
#pragma unroll
    for (int k = 0; k < 3; ++k) {
        m[k] = masks[(size_t)blk * (SH * CPR) + 3 * t + k];
        cnt += (unsigned)__popcll(m[k]);
    }
    unsigned incl = cnt;
#pragma unroll
    for (int o = 1; o < 64; o <<= 1) {
        unsigned u = __shfl_up(incl, o, 64);
        if (lane >= o) incl += u;
    }
    __shared__ unsigned wtot[4];
    if (lane == 63) wtot[wv] = incl;
    __syncthreads();
    unsigned wbase = 0;
#pragma unroll
    for (int k = 0; k < 4; ++k) wbase += (k < wv) ? wtot[k] : 0u;
    unsigned pos = offsets[blk] + wbase + (incl - cnt);
    const int ybase = (blk % 48) * SH;
#pragma unroll
    for (int k = 0; k < 3; ++k) {
        unsigned long long mm = m[k];
        if (mm) {
            const int q = 3 * t + k;
            const int y = ybase + q / CPR;
            const int x0 = (q % CPR) * 64;
            while (mm) {
                int j = __builtin_ctzll(mm);
                mm &= mm - 1ull;
                if (pos < K) { out[pos] = y; out[K + pos] = x0 + j; }
                ++pos;
            }
        }
    }
}

extern "C" void kernel_launch(void* const* d_in, const int* in_sizes, int n_in,
                              void* d_out, int out_size, void* d_ws, size_t ws_size,
                              hipStream_t stream) {
    const float* in = (const float*)d_in[0];
    int* out = (int*)d_out;
    unsigned long long* masks = (unsigned long long*)d_ws;
    unsigned int* counts = (unsigned int*)((char*)d_ws + (size_t)NMASK * 8);
    unsigned int* offsets = counts + NBLK1;
    const unsigned K = (unsigned)(out_size / 2);

    nms_pass1<<<NBLK1, BLOCK1, 0, stream>>>(in, masks, counts);
    nms_scan<<<1, 256, 0, stream>>>(counts, offsets);
    nms_pass3<<<NBLK1, 256, 0, stream>>>(masks, offsets, out, K);
}

// Round 6
// 246.311 us; speedup vs baseline: 3.6739x; 1.0848x over previous
//
#include <hip/hip_runtime.h>

// NonMaxSuppression: 3x3 local max + thr>=0.6 + 10px border -> ordered (y,x) coords.
// Input fixed: (16,1,1536,1536) fp32.
// Pass1: barrier-free rolling-register NMS. Block = 16 rows x 1536 px, thread = 4 cols.
//        Two unaligned (dword-aligned) float4 loads/row give the 6-wide halo window;
//        separable v_max3 vertical window rolls in registers. u64 masks + block counts.
// Pass2: tiny exclusive scan. Pass3: mask replay + ordered (y,x) scatter.
#define W 1536
#define H 1536
#define NB 16
#define NROWS (NB * H)              // 24576
#define SH 16                       // output rows per pass1 block
#define NBLK1 (NROWS / SH)          // 1536
#define BLOCK1 384                  // 1536/4 cols per thread-row
#define CPR 24                      // u64 chunks per row
#define NMASK (NROWS * CPR)         // 589824 u64 = 4.72 MB
#define REP_THR 0.6f

__device__ __forceinline__ float max3f(float a, float b, float c) {
    return fmaxf(fmaxf(a, b), c);  // v_max3_f32
}

// dword-aligned (not 16B-aligned) float4 load
__device__ __forceinline__ float4 ld4u(const float* p) {
    float4 r;
    __builtin_memcpy(&r, p, 16);
    return r;
}

__global__ __launch_bounds__(BLOCK1) void nms_pass1(const float* __restrict__ in,
                                                    unsigned long long* __restrict__ masks,
                                                    unsigned int* __restrict__ counts) {
    const int t = threadIdx.x;
    const int lane = t & 63;
    const int wv = t >> 6;
    const int blk = blockIdx.x;
    const int r0 = blk * SH;                 // first output row (global, = img*H + ytile*SH)
    const int ytile = blk % (H / SH);        // strip index within image

    // column windows: va covers cols 4t-1..4t+2, vb covers 4t+1..4t+4 (clamped at edges;
    // clamped lanes produce garbage only where the x-border mask kills the result)
    const int ca = (t == 0) ? 0 : 4 * t - 1;
    const int cb = (t == BLOCK1 - 1) ? 4 * t : 4 * t + 1;

    // x-border nibble mask, valid x in [10, 1526)
    unsigned colm = 0xFu;
    if (t <= 1) colm = 0u;
    else if (t == 2) colm = 0xCu;
    if (t >= 382) colm = 0u;
    else if (t == 381) colm = 0x3u;

    auto rowp = [&](int i) {                 // input row rel i (rel 0 = r0-1), clamped
        int ir = r0 - 1 + i;
        ir = ir < 0 ? 0 : (ir >= NROWS ? NROWS - 1 : ir);
        return in + (size_t)ir * W;
    };

    // prologue: rows rel 0,1 and prefetch rel 2
    float4 va0 = ld4u(rowp(0) + ca), vb0 = ld4u(rowp(0) + cb);
    float4 va1 = ld4u(rowp(1) + ca), vb1 = ld4u(rowp(1) + cb);
    float4 vaN = ld4u(rowp(2) + ca), vbN = ld4u(rowp(2) + cb);

    float4 hA, hB, ctrB;
    hA.x = max3f(va0.x, va0.y, va0.z);
    hA.y = max3f(va0.y, va0.z, va0.w);
    hA.z = max3f(vb0.x, vb0.y, vb0.z);
    hA.w = max3f(vb0.y, vb0.z, vb0.w);
    hB.x = max3f(va1.x, va1.y, va1.z);
    hB.y = max3f(va1.y, va1.z, va1.w);
    hB.z = max3f(vb1.x, vb1.y, vb1.z);
    hB.w = max3f(vb1.y, vb1.z, vb1.w);
    ctrB.x = va1.y; ctrB.y = va1.z; ctrB.z = va1.w; ctrB.w = vb1.z;

    unsigned cnt = 0;
#pragma unroll
    for (int i = 2; i <= SH + 1; ++i) {
        float4 va = vaN, vb = vbN;
        vaN = ld4u(rowp(i + 1) + ca);        // depth-1 prefetch (clamped; row 18 harmless)
        vbN = ld4u(rowp(i + 1) + cb);
        float4 hC;
        hC.x = max3f(va.x, va.y, va.z);
        hC.y = max3f(va.y, va.z, va.w);
        hC.z = max3f(vb.x, vb.y, vb.z);
        hC.w = max3f(vb.y, vb.z, vb.w);

        const int yloc = ytile * SH + (i - 2);   // image-local y of emitted row
        unsigned nib = 0u;
        if (yloc >= 10 && yloc < H - 10) {
            nib |= (ctrB.x >= fmaxf(max3f(hA.x, hB.x, hC.x), REP_THR)) ? 1u : 0u;
            nib |= (ctrB.y >= fmaxf(max3f(hA.y, hB.y, hC.y), REP_THR)) ? 2u : 0u;
            nib |= (ctrB.z >= fmaxf(max3f(hA.z, hB.z, hC.z), REP_THR)) ? 4u : 0u;
            nib |= (ctrB.w >= fmaxf(max3f(hA.w, hB.w, hC.w), REP_THR)) ? 8u : 0u;
            nib &= colm;
        }
        cnt += __popc(nib);
        // fold 16 lanes' nibbles -> u64 chunk (lane%16==0 stores)
        unsigned x = nib;
        x |= __shfl_down(x, 1, 64) << 4;
        x |= __shfl_down(x, 2, 64) << 8;
        x |= __shfl_down(x, 4, 64) << 16;
        unsigned hi = __shfl_down(x, 8, 64);
        if ((lane & 15) == 0) {
            unsigned long long m64 = (unsigned long long)x | ((unsigned long long)hi << 32);
            masks[(size_t)(r0 + i - 2) * CPR + (t >> 4)] = m64;
        }
        hA = hB; hB = hC;
        ctrB.x = va.y; ctrB.y = va.z; ctrB.z = va.w; ctrB.w = vb.z;
    }

#pragma unroll
    for (int o = 32; o > 0; o >>= 1) cnt += __shfl_down(cnt, o, 64);
    __shared__ unsigned wsum[BLOCK1 / 64];
    if (lane == 0) wsum[wv] = cnt;
    __syncthreads();
    if (t == 0) {
        unsigned s = 0;
#pragma unroll
        for (int k = 0; k < BLOCK1 / 64; ++k) s += wsum[k];
        counts[blk] = s;
    }
}

// Pass 2: exclusive scan of 1536 counts (one block, 256 threads x 6).
__global__ __launch_bounds__(256) void nms_scan(const unsigned int* __restrict__ counts,
                                                unsigned int* __restrict__ offsets) {
    const int t = threadIdx.x;
    const int lane = t & 63, wv = t >> 6;
    unsigned v[6];
    unsigned sum = 0;
#pragma unroll
    for (int k = 0; k < 6; ++k) { v[k] = counts[t * 6 + k]; sum += v[k]; }
    unsigned incl = sum;
#pragma unroll
    for (int o = 1; o < 64; o <<= 1) {
        unsigned u = __shfl_up(incl, o, 64);
        if (lane >= o) incl += u;
    }
    __shared__ unsigned wtot[4];
    if (lane == 63) wtot[wv] = incl;
    __syncthreads();
    unsigned base = incl - sum;
#pragma unroll
    for (int k = 0; k < 4; ++k) base += (k < wv) ? wtot[k] : 0u;
#pragma unroll
    for (int k = 0; k < 6; ++k) { offsets[t * 6 + k] = base; base += v[k]; }
}

// Pass 3: one u64 mask per thread, block scan, ordered (y,x) scatter.
__global__ __launch_bounds__(BLOCK1) void nms_pass3(const unsigned long long* __restrict__ masks,
                                                    const unsigned int* __restrict__ offsets,
                                                    int* __restrict__ out, unsigned int K) {
    const int t = threadIdx.x, lane = t & 63, wv = t >> 6;
    const int blk = blockIdx.x;
    unsigned long long bits = masks[(size_t)blk * (SH * CPR) + t];
    const unsigned cnt = (unsigned)__popcll(bits);
    unsigned incl = cnt;
#pragma unroll
    for (int o = 1; o < 64; o <<= 1) {
        unsigned u = __shfl_up(incl, o, 64);
        if (lane >= o) incl += u;
    }
    __shared__ unsigned wtot[BLOCK1 / 64];
    if (lane == 63) wtot[wv] = incl;
    __syncthreads();
    unsigned wbase = 0;
#pragma unroll
    for (int k = 0; k < BLOCK1 / 64; ++k) wbase += (k < wv) ? wtot[k] : 0u;
    unsigned pos = offsets[blk] + wbase + (incl - cnt);
    if (bits) {
        const int y = (blk % (H / SH)) * SH + t / CPR;   // image-local row
        const int x0 = (t % CPR) * 64;
        while (bits) {
            int j = __builtin_ctzll(bits);
            bits &= bits - 1ull;
            if (pos < K) { out[pos] = y; out[K + pos] = x0 + j; }
            ++pos;
        }
    }
}

extern "C" void kernel_launch(void* const* d_in, const int* in_sizes, int n_in,
                              void* d_out, int out_size, void* d_ws, size_t ws_size,
                              hipStream_t stream) {
    const float* in = (const float*)d_in[0];
    int* out = (int*)d_out;
    unsigned long long* masks = (unsigned long long*)d_ws;
    unsigned int* counts = (unsigned int*)((char*)d_ws + (size_t)NMASK * 8);
    unsigned int* offsets = counts + NBLK1;
    const unsigned K = (unsigned)(out_size / 2);

    nms_pass1<<<NBLK1, BLOCK1, 0, stream>>>(in, masks, counts);
    nms_scan<<<1, 256, 0, stream>>>(counts, offsets);
    nms_pass3<<<NBLK1, BLOCK1, 0, stream>>>(masks, offsets, out, K);
}